// Round 11
// baseline (325.500 us; speedup 1.0000x reference)
//
#include <hip/hip_runtime.h>

// NeRF renderer pipeline for MI355X (gfx950).
// R11: revert to R7's proven-clean gather->LDS(xb) staging (R8-R10's JIT
// gathers let the scheduler hoist global-load dest regs across the MFMA body
// -> spill: 143/47/25 MB WRITE_SIZE, scaling with hoisted regs). Keep R8's
// validated non-MFMA wins: double-buffered acts (4 barriers/tile mcf, 3
// density), shuffle scans, O(N) prefix-sum distortion loss. k_mcf L3 weights
// read from global/L2 (transient) to fit 2x32KB LDS bufs at 2 WG/CU.

typedef float f32x4 __attribute__((ext_vector_type(4)));
typedef __bf16 bf16x8 __attribute__((ext_vector_type(8)));
typedef __bf16 bf16x4 __attribute__((ext_vector_type(4)));
typedef unsigned short u16x8 __attribute__((ext_vector_type(8)));
typedef unsigned short u16x4 __attribute__((ext_vector_type(4)));

#define NRAYS 2048
#define NSTEP 128
#define MIN_NEAR 0.05f

// packed-weight offsets (u16 elements) inside the single Wp buffer
#define OFF_D1 0
#define OFF_D2 8192
#define OFF_D3 73728
#define OFF_C1 77824
#define OFF_C2 86016
#define OFF_C3 151552
#define PACK_TOTAL 155648

__device__ __forceinline__ unsigned short f2bf(float f) {
  __bf16 h = (__bf16)f;             // native v_cvt, RTNE
  return __builtin_bit_cast(unsigned short, h);
}
__device__ __forceinline__ u16x4 pack4(float a, float b, float c, float d) {
  bf16x4 h;
  h[0] = (__bf16)a; h[1] = (__bf16)b; h[2] = (__bf16)c; h[3] = (__bf16)d;
  return __builtin_bit_cast(u16x4, h);
}

__device__ __forceinline__ float ray_zmax(const float* __restrict__ ro,
                                          const float* __restrict__ rd, int r) {
  float ox = ro[r * 3], oy = ro[r * 3 + 1], oz = ro[r * 3 + 2];
  float dx = rd[r * 3], dy = rd[r * 3 + 1], dz = rd[r * 3 + 2];
  float b = ox * dx + oy * dy + oz * dz;
  float c = ox * ox + oy * oy + oz * oz - 1.0f;
  float disc = fmaxf(b * b - c, 0.0f);
  return fmaxf(-b + sqrtf(disc), MIN_NEAR + 1e-3f);
}
__device__ __forceinline__ float z_at(float zmax, int i) {
  float zz = MIN_NEAR + (zmax - MIN_NEAR) * ((float)i / 127.0f);
  return fminf(fmaxf(zz, MIN_NEAR), zmax);
}

// wave-inclusive scan (Hillis-Steele via shfl_up, 64 lanes)
__device__ __forceinline__ float wave_iscan(float v, int lane) {
#pragma unroll
  for (int off = 1; off < 64; off <<= 1) {
    float y = __shfl_up(v, off, 64);
    if (lane >= off) v += y;
  }
  return v;
}
// block-inclusive scan over 256 threads; part = 4 floats; 1 barrier
__device__ __forceinline__ float block_iscan(float v, float* part, int lane, int wid) {
  float s = wave_iscan(v, lane);
  if (lane == 63) part[wid] = s;
  __syncthreads();
  float pre = 0.f;
  if (wid > 0) pre += part[0];
  if (wid > 1) pre += part[1];
  if (wid > 2) pre += part[2];
  return s + pre;
}

// ---------------------------------------------------------------- weight pack
__device__ __forceinline__ void pack_std(const float* __restrict__ W,
                                         unsigned short* __restrict__ dst,
                                         int idx, int K, int Norig, int NT) {
  int per = NT * 512;
  int kt = idx / per, rm = idx % per;
  int nt = rm >> 9, lane = (rm >> 3) & 63, j = rm & 7;
  int k = kt * 32 + ((lane >> 4) << 3) + j;
  int n = nt * 16 + (lane & 15);
  float v = (k < K && n < Norig) ? W[k * Norig + n] : 0.0f;
  dst[idx] = f2bf(v);
}

__global__ void k_pack_all(const float* __restrict__ dW1, const float* __restrict__ dW2,
                           const float* __restrict__ dW3, const float* __restrict__ cW1,
                           const float* __restrict__ cW2, const float* __restrict__ cW3,
                           unsigned short* __restrict__ Wp) {
  int idx = blockIdx.x * 256 + threadIdx.x;
  if (idx < OFF_D2) {
    pack_std(dW1, Wp + OFF_D1, idx - OFF_D1, 3, 256, 16);
  } else if (idx < OFF_D3) {
    pack_std(dW2, Wp + OFF_D2, idx - OFF_D2, 256, 256, 16);
  } else if (idx < OFF_C1) {   // density L3, permuted [geo15|sigma]
    int j2 = idx - OFF_D3;
    int lane = (j2 >> 3) & 63, jj = j2 & 7, kt = j2 >> 9;
    int k = kt * 32 + ((lane >> 4) << 3) + jj;
    int n = lane & 15;
    Wp[idx] = f2bf(dW3[k * 16 + ((n + 1) & 15)]);
  } else if (idx < OFF_C2) {   // color L1: X=[geo0..14,0,dir,0..]
    int j2 = idx - OFF_C1;
    int nt = j2 >> 9, lane = (j2 >> 3) & 63, jj = j2 & 7;
    int k = ((lane >> 4) << 3) + jj;
    int n = nt * 16 + (lane & 15);
    float v = 0.0f;
    if (k < 15) v = cW1[(3 + k) * 256 + n];
    else if (k >= 16 && k < 19) v = cW1[(k - 16) * 256 + n];
    Wp[idx] = f2bf(v);
  } else if (idx < OFF_C3) {
    pack_std(cW2, Wp + OFF_C2, idx - OFF_C2, 256, 256, 16);
  } else if (idx < PACK_TOTAL) {
    pack_std(cW3, Wp + OFF_C3, idx - OFF_C3, 256, 3, 1);
  }
}

// ---------------------------------------------------------------- MFMA helpers
// LDS act layout: h[p][n] at u16 offset p*256 + ((n>>3)^(p&31))*8 + (n&7)
// xb layout: X[p][c] at u16 offset p*32 + ((g^(p&3))*8) + (c&7), g=c>>3

// L1 (K=32): X from LDS xb (R7-proven: short load-to-use ranges), write dst.
__device__ __forceinline__ void mlp_l1(const unsigned short* xb, unsigned short* dst,
                                       const bf16x8 (&w1r)[4], const float* sb1,
                                       int wid, int quad, int col) {
#pragma unroll
  for (int h = 0; h < 2; ++h) {
    f32x4 acc[8];
#pragma unroll
    for (int i = 0; i < 8; ++i) acc[i] = (f32x4){0.f, 0.f, 0.f, 0.f};
    int p0 = (h * 2) * 16 + col, p1 = (h * 2 + 1) * 16 + col;
    bf16x8 x0 = *reinterpret_cast<const bf16x8*>(&xb[p0 * 32 + ((quad ^ (p0 & 3)) * 8)]);
    bf16x8 x1 = *reinterpret_cast<const bf16x8*>(&xb[p1 * 32 + ((quad ^ (p1 & 3)) * 8)]);
#pragma unroll
    for (int ntl = 0; ntl < 4; ++ntl) {
      acc[ntl * 2 + 0] = __builtin_amdgcn_mfma_f32_16x16x32_bf16(w1r[ntl], x0, acc[ntl * 2 + 0], 0, 0, 0);
      acc[ntl * 2 + 1] = __builtin_amdgcn_mfma_f32_16x16x32_bf16(w1r[ntl], x1, acc[ntl * 2 + 1], 0, 0, 0);
    }
#pragma unroll
    for (int ntl = 0; ntl < 4; ++ntl) {
      int n = (wid * 4 + ntl) * 16 + quad * 4;
      f32x4 bv = *reinterpret_cast<const f32x4*>(&sb1[n]);
#pragma unroll
      for (int j = 0; j < 2; ++j) {
        int p = (h * 2 + j) * 16 + col;
        *reinterpret_cast<u16x4*>(&dst[p * 256 + (((n >> 3) ^ (p & 31)) * 8) + (n & 7)]) =
            pack4(fmaxf(acc[ntl * 2 + j][0] + bv[0], 0.f), fmaxf(acc[ntl * 2 + j][1] + bv[1], 0.f),
                  fmaxf(acc[ntl * 2 + j][2] + bv[2], 0.f), fmaxf(acc[ntl * 2 + j][3] + bv[3], 0.f));
      }
    }
  }
}

// L2 half-pass: read src (bufA), write dst (bufB). No barriers inside.
__device__ __forceinline__ void l2_pass(const unsigned short* src, unsigned short* dst,
                                        const bf16x8 (&w2r)[8][4], const float* sb2,
                                        int h, int wid, int quad, int col) {
  f32x4 acc[8];
#pragma unroll
  for (int i = 0; i < 8; ++i) acc[i] = (f32x4){0.f, 0.f, 0.f, 0.f};
  const int p0 = (h * 2) * 16 + col, p1 = (h * 2 + 1) * 16 + col;
#pragma unroll
  for (int kt = 0; kt < 8; ++kt) {
    bf16x8 x0 = *reinterpret_cast<const bf16x8*>(&src[p0 * 256 + (((kt * 4 + quad) ^ (p0 & 31)) * 8)]);
    bf16x8 x1 = *reinterpret_cast<const bf16x8*>(&src[p1 * 256 + (((kt * 4 + quad) ^ (p1 & 31)) * 8)]);
#pragma unroll
    for (int ntl = 0; ntl < 4; ++ntl) {
      acc[ntl * 2 + 0] = __builtin_amdgcn_mfma_f32_16x16x32_bf16(w2r[kt][ntl], x0, acc[ntl * 2 + 0], 0, 0, 0);
      acc[ntl * 2 + 1] = __builtin_amdgcn_mfma_f32_16x16x32_bf16(w2r[kt][ntl], x1, acc[ntl * 2 + 1], 0, 0, 0);
    }
  }
#pragma unroll
  for (int ntl = 0; ntl < 4; ++ntl) {
    int n = (wid * 4 + ntl) * 16 + quad * 4;
    f32x4 bv = *reinterpret_cast<const f32x4*>(&sb2[n]);
#pragma unroll
    for (int j = 0; j < 2; ++j) {
      int p = (h * 2 + j) * 16 + col;
      *reinterpret_cast<u16x4*>(&dst[p * 256 + (((n >> 3) ^ (p & 31)) * 8) + (n & 7)]) =
          pack4(fmaxf(acc[ntl * 2 + j][0] + bv[0], 0.f), fmaxf(acc[ntl * 2 + j][1] + bv[1], 0.f),
                fmaxf(acc[ntl * 2 + j][2] + bv[2], 0.f), fmaxf(acc[ntl * 2 + j][3] + bv[3], 0.f));
    }
  }
}

// ---------------------------------------------------------------- density MLP
template <bool FIRST>
__global__ __launch_bounds__(256, 2)
void k_density(const float* __restrict__ ro, const float* __restrict__ rd,
               const float* __restrict__ zin,
               const unsigned short* __restrict__ Wp1, const float* __restrict__ b1,
               const unsigned short* __restrict__ Wp2, const float* __restrict__ b2,
               const unsigned short* __restrict__ Wp3, const float* __restrict__ b3,
               unsigned short* __restrict__ gout, float* __restrict__ sig,
               float* __restrict__ z_f) {
  __shared__ __align__(16) unsigned short bufA[64 * 256];
  __shared__ __align__(16) unsigned short bufB[64 * 256];
  __shared__ __align__(16) unsigned short xb[64 * 32];
  __shared__ __align__(16) unsigned short sW3[4096];
  __shared__ __align__(16) float sb1[256];
  __shared__ __align__(16) float sb2[256];
  __shared__ __align__(16) float sb3[16];
  __shared__ __align__(16) float ssig[256];
  __shared__ __align__(16) float sred[16];
  const int t = threadIdx.x;
  const int lane = t & 63, wid = t >> 6, quad = lane >> 4, col = lane & 15;
  const int p_ = t >> 2, g_ = t & 3;

  sb1[t] = b1[t];
  sb2[t] = b2[t];
  if (t < 16) sb3[t] = b3[(t + 1) & 15];  // permuted to match pack
  { const u16x8* s = (const u16x8*)Wp3; u16x8* d = (u16x8*)sW3;
    d[t] = s[t]; d[t + 256] = s[t + 256]; }

  bf16x8 w1r[4], w2r[8][4];
#pragma unroll
  for (int ntl = 0; ntl < 4; ++ntl)
    w1r[ntl] = *reinterpret_cast<const bf16x8*>(Wp1 + ((wid * 4 + ntl) * 64 + lane) * 8);
#pragma unroll
  for (int kt = 0; kt < 8; ++kt)
#pragma unroll
    for (int ntl = 0; ntl < 4; ++ntl)
      w2r[kt][ntl] = *reinterpret_cast<const bf16x8*>(Wp2 + ((kt * 16 + wid * 4 + ntl) * 64 + lane) * 8);

  // WG's 2 rays, register-resident params
  const int rg0 = blockIdx.x * 2;
  float zmax0 = ray_zmax(ro, rd, rg0);
  float zmax1 = ray_zmax(ro, rd, rg0 + 1);
  float oax = ro[rg0 * 3], oay = ro[rg0 * 3 + 1], oaz = ro[rg0 * 3 + 2];
  float dax = rd[rg0 * 3], day = rd[rg0 * 3 + 1], daz = rd[rg0 * 3 + 2];
  float obx = ro[rg0 * 3 + 3], oby = ro[rg0 * 3 + 4], obz = ro[rg0 * 3 + 5];
  float dbx = rd[rg0 * 3 + 3], dby = rd[rg0 * 3 + 4], dbz = rd[rg0 * 3 + 5];
  __syncthreads();  // staging done

#pragma unroll 1
  for (int tt = 0; tt < 4; ++tt) {
    const int P0 = blockIdx.x * 256 + tt * 64;
    { // build X = [x,y,z,0..] -> LDS xb (R7-proven staging)
      u16x8 pk = {0, 0, 0, 0, 0, 0, 0, 0};
      if (g_ == 0) {
        int P = P0 + p_;
        int hi = (P >> 7) & 1;
        float zz;
        if constexpr (FIRST) zz = z_at(hi ? zmax1 : zmax0, P & 127);
        else zz = zin[P];
        pk[0] = f2bf((hi ? obx : oax) + (hi ? dbx : dax) * zz);
        pk[1] = f2bf((hi ? oby : oay) + (hi ? dby : day) * zz);
        pk[2] = f2bf((hi ? obz : oaz) + (hi ? dbz : daz) * zz);
      }
      *reinterpret_cast<u16x8*>(&xb[p_ * 32 + ((g_ ^ (p_ & 3)) * 8)]) = pk;
    }
    __syncthreads();  // B1: xb ready
    mlp_l1(xb, bufA, w1r, sb1, wid, quad, col);
    __syncthreads();  // B2: h1 visible
    l2_pass(bufA, bufB, w2r, sb2, 0, wid, quad, col);
    l2_pass(bufA, bufB, w2r, sb2, 1, wid, quad, col);
    __syncthreads();  // B3: h2 visible
    { // L3: 256 -> 16 permuted [geo15 | sigma]
      const int p = wid * 16 + col;
      f32x4 a3 = {0.f, 0.f, 0.f, 0.f};
#pragma unroll
      for (int kt = 0; kt < 8; ++kt) {
        bf16x8 w = *reinterpret_cast<const bf16x8*>(&sW3[(kt * 64 + lane) * 8]);
        bf16x8 xx = *reinterpret_cast<const bf16x8*>(&bufB[p * 256 + (((kt * 4 + quad) ^ (p & 31)) * 8)]);
        a3 = __builtin_amdgcn_mfma_f32_16x16x32_bf16(w, xx, a3, 0, 0, 0);
      }
      int n0 = quad * 4;
      float v0 = a3[0] + sb3[n0], v1 = a3[1] + sb3[n0 + 1];
      float v2 = a3[2] + sb3[n0 + 2], v3 = a3[3] + sb3[n0 + 3];
      if (quad == 3) {  // sigma: trunc_exp -> sig[], gout slot = 0
        float sgm = __expf(fminf(fmaxf(v3, -15.f), 15.f));
        sig[P0 + p] = sgm;
        if constexpr (FIRST) ssig[tt * 64 + p] = sgm;
        v3 = 0.0f;
      }
      *reinterpret_cast<u16x4*>(gout + (size_t)(P0 + p) * 16 + n0) = pack4(v0, v1, v2, v3);
    }
  }

  if constexpr (FIRST) {  // fused sample_pdf (shuffle scans; scratch in bufA)
    __syncthreads();  // ssig ready; bufA/bufB free
    float* psz = reinterpret_cast<float*>(bufA);   // [256]
    float* pmid = psz + 256;                       // [256]
    float* pcdf = psz + 512;                       // [256]
    float* psw = psz + 768;                        // [256] (reused as sl)
    const int segw = t >> 7;
    const int i = t & 127;
    const int seg = segw * 128;
    float zi = z_at(segw ? zmax1 : zmax0, i);
    psz[seg + i] = zi;
    float sgv = ssig[t];
    __syncthreads();
    float aug = (i < 127) ? psz[seg + i + 1] - zi : psz[seg + 127] - psz[seg + 126];
    float alpha = 1.0f - __expf(-aug * sgv);
    float lt = __logf(1.0f - alpha + 1e-15f);
    float s = wave_iscan(lt, lane);        // segmented 128-scan: 2 waves/segment
    if (lane == 63) sred[wid] = s;
    __syncthreads();
    if (wid & 1) s += sred[wid - 1];
    float w = alpha * __expf(s - lt);
    psw[seg + i] = w;
    if (i < 127) pmid[seg + i] = 0.5f * (zi + psz[seg + i + 1]);
    __syncthreads();
    float v2s = (i < 126) ? psw[seg + i + 1] + 1e-5f : 0.f;  // weights[1:-1]+1e-5
    float s2 = wave_iscan(v2s, lane);
    if (lane == 63) sred[8 + wid] = s2;
    __syncthreads();
    if (wid & 1) s2 += sred[8 + wid - 1];
    psw[seg + i] = s2;
    __syncthreads();
    float total = psw[seg + 125];
    if (i <= 126) pcdf[seg + i] = (i == 0) ? 0.f : psw[seg + i - 1] / total;
    __syncthreads();
    const float lo = 0.5f / 128.0f, hi = 1.0f - 0.5f / 128.0f;
    float u = lo + (hi - lo) * ((float)i / 127.0f);
    int loI = 0, hiI = 127;  // searchsorted right over pcdf[seg+0..126]
    while (loI < hiI) {
      int mid = (loI + hiI) >> 1;
      if (pcdf[seg + mid] > u) hiI = mid; else loI = mid + 1;
    }
    int below = loI - 1; if (below < 0) below = 0; if (below > 126) below = 126;
    int above = loI;     if (above > 126) above = 126;
    float c0 = pcdf[seg + below], c1 = pcdf[seg + above];
    float b0v = pmid[seg + below], b1v = pmid[seg + above];
    float dn = c1 - c0; if (dn < 1e-5f) dn = 1.0f;
    float ttt = (u - c0) / dn;
    z_f[(rg0 + segw) * NSTEP + i] = b0v + ttt * (b1v - b0v);
  }
}

// --------------------------------------- merge + color MLP + final (per ray)
__global__ __launch_bounds__(256, 2)
void k_mcf(const float* __restrict__ ro, const float* __restrict__ rd,
           const float* __restrict__ z_f,
           const float* __restrict__ sigc, const float* __restrict__ sigf,
           const unsigned short* __restrict__ goutc, const unsigned short* __restrict__ goutf,
           const unsigned short* __restrict__ Wp1, const float* __restrict__ cb1,
           const unsigned short* __restrict__ Wp2, const float* __restrict__ cb2,
           const unsigned short* __restrict__ Wp3, const float* __restrict__ cb3,
           float* __restrict__ out) {
  __shared__ __align__(16) unsigned short bufA[64 * 256];
  __shared__ __align__(16) unsigned short bufB[64 * 256];
  __shared__ __align__(16) unsigned short xb[64 * 32];
  __shared__ __align__(16) float sb1[256];
  __shared__ __align__(16) float sb2[256];
  __shared__ __align__(16) float szm[256];
  __shared__ __align__(16) float swgt[256];
  __shared__ __align__(16) float srgb[768];
  __shared__ __align__(16) float sred[48];
  __shared__ unsigned short sord[256];
  const int t = threadIdx.x;
  const int lane = t & 63, wid = t >> 6, quad = lane >> 4, col = lane & 15;
  const int p_ = t >> 2, g_ = t & 3;
  const int r = blockIdx.x;

  sb1[t] = cb1[t];
  sb2[t] = cb2[t];

  bf16x8 w1r[4], w2r[8][4];
#pragma unroll
  for (int ntl = 0; ntl < 4; ++ntl)
    w1r[ntl] = *reinterpret_cast<const bf16x8*>(Wp1 + ((wid * 4 + ntl) * 64 + lane) * 8);
#pragma unroll
  for (int kt = 0; kt < 8; ++kt)
#pragma unroll
    for (int ntl = 0; ntl < 4; ++ntl)
      w2r[kt][ntl] = *reinterpret_cast<const bf16x8*>(Wp2 + ((kt * 16 + wid * 4 + ntl) * 64 + lane) * 8);

  // ---- merge phase (stable sort of coarse+fine z); scratch aliased in bufA
  float* szc = reinterpret_cast<float*>(bufA);
  float* szf = szc + 128;
  float zmaxr = ray_zmax(ro, rd, r);
  if (t < 128) szc[t] = z_at(zmaxr, t);
  else szf[t - 128] = z_f[r * NSTEP + (t - 128)];
  __syncthreads();
  int pos; float myz;
  if (t < 128) {  // coarse i: pos = i + #{zf < zc[i]} (ties: coarse first)
    myz = szc[t];
    int lo = 0, hi = 128;
    while (lo < hi) { int m = (lo + hi) >> 1; if (szf[m] < myz) lo = m + 1; else hi = m; }
    pos = t + lo;
  } else {        // fine j: pos = j + #{zc <= zf[j]}
    int j = t - 128; myz = szf[j];
    int lo = 0, hi = 128;
    while (lo < hi) { int m = (lo + hi) >> 1; if (szc[m] <= myz) lo = m + 1; else hi = m; }
    pos = j + lo;
  }
  szm[pos] = myz; sord[pos] = (unsigned short)t;
  __syncthreads();
  int srci = sord[t];
  float sg = (srci < 128) ? sigc[r * NSTEP + srci] : sigf[r * NSTEP + (srci - 128)];
  float zt = szm[t];
  float aug = (t < 255) ? szm[t + 1] - zt : szm[255] - szm[254];
  float alpha = 1.0f - __expf(-aug * sg);
  float lt = __logf(1.0f - alpha + 1e-15f);
  float incl = block_iscan(lt, sred, lane, wid);  // 1 barrier
  swgt[t] = alpha * __expf(incl - lt);
  __syncthreads();  // swgt/sord ready; bufA scratch handoff

  // ---- color phase: 4 tiles; R7-proven staged gather pipeline -> LDS xb
  float dv0 = rd[r * 3], dv1 = rd[r * 3 + 1], dv2 = rd[r * 3 + 2];
  u16x8 dirpk = {f2bf(dv0), f2bf(dv1), f2bf(dv2), 0, 0, 0, 0, 0};
  u16x8 gx = {0, 0, 0, 0, 0, 0, 0, 0};
  float wgtv = 0.0f;
  { // prologue gather (tile 0)
    if (g_ < 2) {
      int s0 = sord[p_];
      const unsigned short* gs = ((s0 < 128) ? goutc : goutf)
          + ((size_t)(r * NSTEP + (s0 & 127)) * 16) + g_ * 8;
      gx = *reinterpret_cast<const u16x8*>(gs);
    } else if (g_ == 2) {
      gx = dirpk;
    } else {
      wgtv = swgt[p_];
    }
  }
#pragma unroll 1
  for (int tt = 0; tt < 4; ++tt) {
    const int haveNext = (tt < 3);
    int go = __syncthreads_or((g_ == 3) && (wgtv > 1e-4f));
    int ordn = 0; float wgtn = 0.0f;
    u16x8 gxn = {0, 0, 0, 0, 0, 0, 0, 0};
    if (go) {
      *reinterpret_cast<u16x8*>(&xb[p_ * 32 + ((g_ ^ (p_ & 3)) * 8)]) = gx;
      __syncthreads();  // B1: xb ready
      mlp_l1(xb, bufA, w1r, sb1, wid, quad, col);
      __syncthreads();  // B2: h1 visible
    }
    if (haveNext) {  // stage 1: LDS order/wgt + uniform dir
      int Pn = (tt + 1) * 64 + p_;
      if (g_ < 2) ordn = sord[Pn];
      else if (g_ == 2) gxn = dirpk;
      else wgtn = swgt[Pn];
    }
    if (go) {
      l2_pass(bufA, bufB, w2r, sb2, 0, wid, quad, col);
      l2_pass(bufA, bufB, w2r, sb2, 1, wid, quad, col);
    }
    if (haveNext && g_ < 2) {  // stage 2: global gout gather
      const unsigned short* gs = ((ordn < 128) ? goutc : goutf)
          + ((size_t)(r * NSTEP + (ordn & 127)) * 16) + g_ * 8;
      gxn = *reinterpret_cast<const u16x8*>(gs);
    }
    if (go) {
      __syncthreads();  // B3: h2 visible
      { // L3: 256 -> 3, sigmoid -> srgb; Wp3 from global/L2 (transient)
        const int p = wid * 16 + col;
        f32x4 a3 = {0.f, 0.f, 0.f, 0.f};
#pragma unroll
        for (int kt = 0; kt < 8; ++kt) {
          bf16x8 w = *reinterpret_cast<const bf16x8*>(&Wp3[(kt * 64 + lane) * 8]);
          bf16x8 xx = *reinterpret_cast<const bf16x8*>(&bufB[p * 256 + (((kt * 4 + quad) ^ (p & 31)) * 8)]);
          a3 = __builtin_amdgcn_mfma_f32_16x16x32_bf16(w, xx, a3, 0, 0, 0);
        }
        if (quad == 0) {
          int pi = tt * 64 + p;
          srgb[pi * 3 + 0] = 1.0f / (1.0f + __expf(-(a3[0] + cb3[0])));
          srgb[pi * 3 + 1] = 1.0f / (1.0f + __expf(-(a3[1] + cb3[1])));
          srgb[pi * 3 + 2] = 1.0f / (1.0f + __expf(-(a3[2] + cb3[2])));
        }
      }
    }
    gx = gxn; wgtv = wgtn;
  }

  // ---- final: image/depth + distortion loss via sorted prefix sums
  __syncthreads();  // srgb ready
  float ztf = szm[t], wtf = swgt[t];
  float znext = (t < 255) ? szm[t + 1] : (1.0f / 128.0f);  // sample_dist
  float mt = 0.5f * ztf + 0.5f * znext;  // sorted for t<=254; t=255 is outlier
  float cr = 0.f, cg = 0.f, cbl = 0.f;
  if (wtf > 1e-4f) { cr = srgb[t * 3]; cg = srgb[t * 3 + 1]; cbl = srgb[t * 3 + 2]; }
  if (t == 255) { sred[36] = mt; sred[37] = wtf; }
  float wm = (t < 255) ? wtf : 0.f;
  float Pw = block_iscan(wm, sred, lane, wid);
  float Ps = block_iscan(wm * mt, sred + 4, lane, wid);
  float W254 = sred[0] + sred[1] + sred[2] + sred[3];
  float S254 = sred[4] + sred[5] + sred[6] + sred[7];
  float m255 = sred[36], w255 = sred[37];
  float contrib = 0.f;
  if (t < 255)
    contrib = wtf * (mt * (2.f * Pw - W254) - (2.f * Ps - S254))
            + 2.f * wtf * fabsf(mt - m255) * w255;
  float vals[6] = {wtf, wtf * ztf, wtf * cr, wtf * cg, wtf * cbl, contrib};
#pragma unroll
  for (int k = 0; k < 6; ++k) {
    float v = vals[k];
#pragma unroll
    for (int m = 1; m < 64; m <<= 1) v += __shfl_xor(v, m, 64);
    if (lane == 0) sred[8 + k * 4 + wid] = v;
  }
  __syncthreads();
  if (t == 0) {
    float a6[6];
#pragma unroll
    for (int k = 0; k < 6; ++k)
      a6[k] = sred[8 + k * 4] + sred[8 + k * 4 + 1] + sred[8 + k * 4 + 2] + sred[8 + k * 4 + 3];
    const float bgc = 206.0f / 255.0f;
    float wsum = a6[0], depth = a6[1];
    float loss = a6[5] / (depth + 1e-6f);
    if (loss < 1e-3f) loss = 0.0f;
    out[r * 5 + 0] = a6[2] + (1.0f - wsum) * bgc;
    out[r * 5 + 1] = a6[3] + (1.0f - wsum) * bgc;
    out[r * 5 + 2] = a6[4] + (1.0f - wsum) * bgc;
    out[r * 5 + 3] = depth;
    out[r * 5 + 4] = loss;
  }
}

// ---------------------------------------------------------------- launch
extern "C" void kernel_launch(void* const* d_in, const int* in_sizes, int n_in,
                              void* d_out, int out_size, void* d_ws, size_t ws_size,
                              hipStream_t stream) {
  const float* rays_o = (const float*)d_in[0];
  const float* rays_d = (const float*)d_in[1];
  const float* dW1 = (const float*)d_in[2];
  const float* db1 = (const float*)d_in[3];
  const float* dW2 = (const float*)d_in[4];
  const float* db2 = (const float*)d_in[5];
  const float* dW3 = (const float*)d_in[6];
  const float* db3 = (const float*)d_in[7];
  const float* cW1 = (const float*)d_in[8];
  const float* cb1 = (const float*)d_in[9];
  const float* cW2 = (const float*)d_in[10];
  const float* cb2 = (const float*)d_in[11];
  const float* cW3 = (const float*)d_in[12];
  const float* cb3 = (const float*)d_in[13];
  // num_steps / upsample_steps fixed at 128/128 (compile-time).

  char* ws = (char*)d_ws;
  size_t off = 0;
  auto alloc = [&](size_t bytes) -> void* {
    void* p = ws + off;
    off += (bytes + 255) & ~(size_t)255;
    return p;
  };
  unsigned short* Wp = (unsigned short*)alloc((size_t)PACK_TOTAL * 2);
  unsigned short* goutc = (unsigned short*)alloc((size_t)NRAYS * NSTEP * 16 * 2);
  unsigned short* goutf = (unsigned short*)alloc((size_t)NRAYS * NSTEP * 16 * 2);
  float* sigc = (float*)alloc((size_t)NRAYS * NSTEP * 4);
  float* sigf = (float*)alloc((size_t)NRAYS * NSTEP * 4);
  float* z_f  = (float*)alloc((size_t)NRAYS * NSTEP * 4);
  (void)ws_size; (void)in_sizes; (void)n_in; (void)out_size;

  k_pack_all<<<PACK_TOTAL / 256, 256, 0, stream>>>(dW1, dW2, dW3, cW1, cW2, cW3, Wp);

  k_density<true><<<(NRAYS * NSTEP) / 256, 256, 0, stream>>>(
      rays_o, rays_d, nullptr,
      Wp + OFF_D1, db1, Wp + OFF_D2, db2, Wp + OFF_D3, db3, goutc, sigc, z_f);
  k_density<false><<<(NRAYS * NSTEP) / 256, 256, 0, stream>>>(
      rays_o, rays_d, z_f,
      Wp + OFF_D1, db1, Wp + OFF_D2, db2, Wp + OFF_D3, db3, goutf, sigf, nullptr);
  k_mcf<<<NRAYS, 256, 0, stream>>>(
      rays_o, rays_d, z_f, sigc, sigf, goutc, goutf,
      Wp + OFF_C1, cb1, Wp + OFF_C2, cb2, Wp + OFF_C3, cb3, (float*)d_out);
}

// Round 12
// 272.148 us; speedup vs baseline: 1.1960x; 1.1960x over previous
//
#include <hip/hip_runtime.h>

// NeRF renderer pipeline for MI355X (gfx950).
// R12: R7's MFMA core EXACTLY (single act buffer, in-place L2 half-passes
// with a barrier between compute and write — that barrier doubles as the
// scheduling fence that kept R7 spill-free; LDS sW3; xb gather staging;
// gx/gxn 2-stage pipeline). Grafted: validated shuffle-scan merge (1 barrier),
// shuffle pdf tail, prefix-sum distortion loss (R8-R11 numerics, passed 4x).
// R11's spill came from removing the mid-L2 fence + global Wp3 loads.

typedef float f32x4 __attribute__((ext_vector_type(4)));
typedef __bf16 bf16x8 __attribute__((ext_vector_type(8)));
typedef __bf16 bf16x4 __attribute__((ext_vector_type(4)));
typedef unsigned short u16x8 __attribute__((ext_vector_type(8)));
typedef unsigned short u16x4 __attribute__((ext_vector_type(4)));

#define NRAYS 2048
#define NSTEP 128
#define MIN_NEAR 0.05f

// packed-weight offsets (u16 elements) inside the single Wp buffer
#define OFF_D1 0
#define OFF_D2 8192
#define OFF_D3 73728
#define OFF_C1 77824
#define OFF_C2 86016
#define OFF_C3 151552
#define PACK_TOTAL 155648

__device__ __forceinline__ unsigned short f2bf(float f) {
  __bf16 h = (__bf16)f;             // native v_cvt, RTNE
  return __builtin_bit_cast(unsigned short, h);
}
__device__ __forceinline__ u16x4 pack4(float a, float b, float c, float d) {
  bf16x4 h;
  h[0] = (__bf16)a; h[1] = (__bf16)b; h[2] = (__bf16)c; h[3] = (__bf16)d;
  return __builtin_bit_cast(u16x4, h);
}

// per-ray z for step i (identical arithmetic everywhere for consistency)
__device__ __forceinline__ float ray_z(const float* __restrict__ ro,
                                       const float* __restrict__ rd, int r, int i) {
  float ox = ro[r * 3], oy = ro[r * 3 + 1], oz = ro[r * 3 + 2];
  float dx = rd[r * 3], dy = rd[r * 3 + 1], dz = rd[r * 3 + 2];
  float b = ox * dx + oy * dy + oz * dz;
  float c = ox * ox + oy * oy + oz * oz - 1.0f;
  float disc = fmaxf(b * b - c, 0.0f);
  float zmax = fmaxf(-b + sqrtf(disc), MIN_NEAR + 1e-3f);
  float zmin = MIN_NEAR;
  float tt = (float)i / 127.0f;
  float zz = zmin + (zmax - zmin) * tt;
  return fminf(fmaxf(zz, zmin), zmax);
}

// wave-inclusive scan (Hillis-Steele via shfl_up, 64 lanes)
__device__ __forceinline__ float wave_iscan(float v, int lane) {
#pragma unroll
  for (int off = 1; off < 64; off <<= 1) {
    float y = __shfl_up(v, off, 64);
    if (lane >= off) v += y;
  }
  return v;
}
// block-inclusive scan over 256 threads; part = 4 floats; 1 barrier
__device__ __forceinline__ float block_iscan(float v, float* part, int lane, int wid) {
  float s = wave_iscan(v, lane);
  if (lane == 63) part[wid] = s;
  __syncthreads();
  float pre = 0.f;
  if (wid > 0) pre += part[0];
  if (wid > 1) pre += part[1];
  if (wid > 2) pre += part[2];
  return s + pre;
}

// ---------------------------------------------------------------- weight pack
__device__ __forceinline__ void pack_std(const float* __restrict__ W,
                                         unsigned short* __restrict__ dst,
                                         int idx, int K, int Norig, int NT) {
  int per = NT * 512;
  int kt = idx / per, rm = idx % per;
  int nt = rm >> 9, lane = (rm >> 3) & 63, j = rm & 7;
  int k = kt * 32 + ((lane >> 4) << 3) + j;
  int n = nt * 16 + (lane & 15);
  float v = (k < K && n < Norig) ? W[k * Norig + n] : 0.0f;
  dst[idx] = f2bf(v);
}

__global__ void k_pack_all(const float* __restrict__ dW1, const float* __restrict__ dW2,
                           const float* __restrict__ dW3, const float* __restrict__ cW1,
                           const float* __restrict__ cW2, const float* __restrict__ cW3,
                           unsigned short* __restrict__ Wp) {
  int idx = blockIdx.x * 256 + threadIdx.x;
  if (idx < OFF_D2) {
    pack_std(dW1, Wp + OFF_D1, idx - OFF_D1, 3, 256, 16);
  } else if (idx < OFF_D3) {
    pack_std(dW2, Wp + OFF_D2, idx - OFF_D2, 256, 256, 16);
  } else if (idx < OFF_C1) {   // density L3, permuted [geo15|sigma]
    int j2 = idx - OFF_D3;
    int lane = (j2 >> 3) & 63, jj = j2 & 7, kt = j2 >> 9;
    int k = kt * 32 + ((lane >> 4) << 3) + jj;
    int n = lane & 15;
    Wp[idx] = f2bf(dW3[k * 16 + ((n + 1) & 15)]);
  } else if (idx < OFF_C2) {   // color L1: X=[geo0..14,0,dir,0..]
    int j2 = idx - OFF_C1;
    int nt = j2 >> 9, lane = (j2 >> 3) & 63, jj = j2 & 7;
    int k = ((lane >> 4) << 3) + jj;
    int n = nt * 16 + (lane & 15);
    float v = 0.0f;
    if (k < 15) v = cW1[(3 + k) * 256 + n];
    else if (k >= 16 && k < 19) v = cW1[(k - 16) * 256 + n];
    Wp[idx] = f2bf(v);
  } else if (idx < OFF_C3) {
    pack_std(cW2, Wp + OFF_C2, idx - OFF_C2, 256, 256, 16);
  } else if (idx < PACK_TOTAL) {
    pack_std(cW3, Wp + OFF_C3, idx - OFF_C3, 256, 3, 1);
  }
}

// ---------------------------------------------------------------- MFMA helpers
// LDS act layout: h[p][n] at u16 offset p*256 + ((n>>3)^(p&31))*8 + (n&7)
// xb layout: X[p][c] at u16 offset p*32 + ((g^(p&3))*8) + (c&7), g=c>>3

__device__ __forceinline__ void mlp_l1(const unsigned short* xb, unsigned short* buf,
                                       const bf16x8 (&w1r)[4], const float* sb1,
                                       int wid, int quad, int col) {
#pragma unroll
  for (int h = 0; h < 2; ++h) {
    f32x4 acc[8];
#pragma unroll
    for (int i = 0; i < 8; ++i) acc[i] = (f32x4){0.f, 0.f, 0.f, 0.f};
    int p0 = (h * 2) * 16 + col, p1 = (h * 2 + 1) * 16 + col;
    bf16x8 x0 = *reinterpret_cast<const bf16x8*>(&xb[p0 * 32 + ((quad ^ (p0 & 3)) * 8)]);
    bf16x8 x1 = *reinterpret_cast<const bf16x8*>(&xb[p1 * 32 + ((quad ^ (p1 & 3)) * 8)]);
#pragma unroll
    for (int ntl = 0; ntl < 4; ++ntl) {
      acc[ntl * 2 + 0] = __builtin_amdgcn_mfma_f32_16x16x32_bf16(w1r[ntl], x0, acc[ntl * 2 + 0], 0, 0, 0);
      acc[ntl * 2 + 1] = __builtin_amdgcn_mfma_f32_16x16x32_bf16(w1r[ntl], x1, acc[ntl * 2 + 1], 0, 0, 0);
    }
#pragma unroll
    for (int ntl = 0; ntl < 4; ++ntl) {
      int n = (wid * 4 + ntl) * 16 + quad * 4;
      f32x4 bv = *reinterpret_cast<const f32x4*>(&sb1[n]);
#pragma unroll
      for (int j = 0; j < 2; ++j) {
        int p = (h * 2 + j) * 16 + col;
        *reinterpret_cast<u16x4*>(&buf[p * 256 + (((n >> 3) ^ (p & 31)) * 8) + (n & 7)]) =
            pack4(fmaxf(acc[ntl * 2 + j][0] + bv[0], 0.f), fmaxf(acc[ntl * 2 + j][1] + bv[1], 0.f),
                  fmaxf(acc[ntl * 2 + j][2] + bv[2], 0.f), fmaxf(acc[ntl * 2 + j][3] + bv[3], 0.f));
      }
    }
  }
}

// L2 half-pass compute (reads buf); caller barriers before l2_half_write
// overwrites buf in place — the barrier doubles as a scheduling fence.
__device__ __forceinline__ void l2_half_compute(const unsigned short* buf,
                                                const bf16x8 (&w2r)[8][4],
                                                f32x4 (&acc)[8], int h, int quad, int col) {
#pragma unroll
  for (int i = 0; i < 8; ++i) acc[i] = (f32x4){0.f, 0.f, 0.f, 0.f};
#pragma unroll
  for (int kt = 0; kt < 8; ++kt) {
    int p0 = (h * 2) * 16 + col, p1 = (h * 2 + 1) * 16 + col;
    bf16x8 x0 = *reinterpret_cast<const bf16x8*>(&buf[p0 * 256 + (((kt * 4 + quad) ^ (p0 & 31)) * 8)]);
    bf16x8 x1 = *reinterpret_cast<const bf16x8*>(&buf[p1 * 256 + (((kt * 4 + quad) ^ (p1 & 31)) * 8)]);
#pragma unroll
    for (int ntl = 0; ntl < 4; ++ntl) {
      acc[ntl * 2 + 0] = __builtin_amdgcn_mfma_f32_16x16x32_bf16(w2r[kt][ntl], x0, acc[ntl * 2 + 0], 0, 0, 0);
      acc[ntl * 2 + 1] = __builtin_amdgcn_mfma_f32_16x16x32_bf16(w2r[kt][ntl], x1, acc[ntl * 2 + 1], 0, 0, 0);
    }
  }
}

__device__ __forceinline__ void l2_half_write(unsigned short* buf, const f32x4 (&acc)[8],
                                              const float* sb2, int h, int wid, int quad, int col) {
#pragma unroll
  for (int ntl = 0; ntl < 4; ++ntl) {
    int n = (wid * 4 + ntl) * 16 + quad * 4;
    f32x4 bv = *reinterpret_cast<const f32x4*>(&sb2[n]);
#pragma unroll
    for (int j = 0; j < 2; ++j) {
      int p = (h * 2 + j) * 16 + col;
      *reinterpret_cast<u16x4*>(&buf[p * 256 + (((n >> 3) ^ (p & 31)) * 8) + (n & 7)]) =
          pack4(fmaxf(acc[ntl * 2 + j][0] + bv[0], 0.f), fmaxf(acc[ntl * 2 + j][1] + bv[1], 0.f),
                fmaxf(acc[ntl * 2 + j][2] + bv[2], 0.f), fmaxf(acc[ntl * 2 + j][3] + bv[3], 0.f));
    }
  }
}

// ---------------------------------------------------------------- density MLP
// FIRST: z computed inline + fused sample_pdf tail -> z_f.  !FIRST: z = zin.
template <bool FIRST>
__global__ __launch_bounds__(256, 2)
void k_density(const float* __restrict__ ro, const float* __restrict__ rd,
               const float* __restrict__ zin,
               const unsigned short* __restrict__ Wp1, const float* __restrict__ b1,
               const unsigned short* __restrict__ Wp2, const float* __restrict__ b2,
               const unsigned short* __restrict__ Wp3, const float* __restrict__ b3,
               unsigned short* __restrict__ gout, float* __restrict__ sig,
               float* __restrict__ z_f) {
  __shared__ __align__(16) unsigned short buf[64 * 256];
  __shared__ __align__(16) unsigned short xb[64 * 32];
  __shared__ __align__(16) unsigned short sW3[4096];
  __shared__ __align__(16) float sb1[256];
  __shared__ __align__(16) float sb2[256];
  __shared__ __align__(16) float sb3[16];
  __shared__ __align__(16) float ssig[256];
  __shared__ __align__(16) float sred[16];
  const int t = threadIdx.x;
  const int lane = t & 63, wid = t >> 6, quad = lane >> 4, col = lane & 15;
  const int p_ = t >> 2, g_ = t & 3;

  sb1[t] = b1[t];
  sb2[t] = b2[t];
  if (t < 16) sb3[t] = b3[(t + 1) & 15];  // permuted to match pack
  { const u16x8* s = (const u16x8*)Wp3; u16x8* d = (u16x8*)sW3;
    d[t] = s[t]; d[t + 256] = s[t + 256]; }

  bf16x8 w1r[4], w2r[8][4];
#pragma unroll
  for (int ntl = 0; ntl < 4; ++ntl)
    w1r[ntl] = *reinterpret_cast<const bf16x8*>(Wp1 + ((wid * 4 + ntl) * 64 + lane) * 8);
#pragma unroll
  for (int kt = 0; kt < 8; ++kt)
#pragma unroll
    for (int ntl = 0; ntl < 4; ++ntl)
      w2r[kt][ntl] = *reinterpret_cast<const bf16x8*>(Wp2 + ((kt * 16 + wid * 4 + ntl) * 64 + lane) * 8);

#pragma unroll 1
  for (int tt = 0; tt < 4; ++tt) {
    const int P0 = blockIdx.x * 256 + tt * 64;
    { // build X = [x,y,z,0..] -> LDS xb (transient scalar loads, R7-proven)
      u16x8 pk = {0, 0, 0, 0, 0, 0, 0, 0};
      if (g_ == 0) {
        int P = P0 + p_;
        int rr_ = P >> 7, ii = P & 127;
        float zz;
        if constexpr (FIRST) zz = ray_z(ro, rd, rr_, ii);
        else zz = zin[P];
        pk[0] = f2bf(ro[rr_ * 3 + 0] + rd[rr_ * 3 + 0] * zz);
        pk[1] = f2bf(ro[rr_ * 3 + 1] + rd[rr_ * 3 + 1] * zz);
        pk[2] = f2bf(ro[rr_ * 3 + 2] + rd[rr_ * 3 + 2] * zz);
      }
      *reinterpret_cast<u16x8*>(&xb[p_ * 32 + ((g_ ^ (p_ & 3)) * 8)]) = pk;
    }
    __syncthreads();  // xb ready; prev tile's L3 buf-reads retired
    mlp_l1(xb, buf, w1r, sb1, wid, quad, col);
    __syncthreads();  // h1 complete
    f32x4 acc[8];
    l2_half_compute(buf, w2r, acc, 0, quad, col);
    __syncthreads();  // fence: half0 reads done before in-place overwrite
    l2_half_write(buf, acc, sb2, 0, wid, quad, col);
    l2_half_compute(buf, w2r, acc, 1, quad, col);
    __syncthreads();  // fence: half1 reads done
    l2_half_write(buf, acc, sb2, 1, wid, quad, col);
    __syncthreads();  // h2 complete
    { // L3: 256 -> 16 permuted [geo15 | sigma]
      const int p = wid * 16 + col;
      f32x4 a3 = {0.f, 0.f, 0.f, 0.f};
#pragma unroll
      for (int kt = 0; kt < 8; ++kt) {
        bf16x8 w = *reinterpret_cast<const bf16x8*>(&sW3[(kt * 64 + lane) * 8]);
        bf16x8 xx = *reinterpret_cast<const bf16x8*>(&buf[p * 256 + (((kt * 4 + quad) ^ (p & 31)) * 8)]);
        a3 = __builtin_amdgcn_mfma_f32_16x16x32_bf16(w, xx, a3, 0, 0, 0);
      }
      int n0 = quad * 4;
      float v0 = a3[0] + sb3[n0], v1 = a3[1] + sb3[n0 + 1];
      float v2 = a3[2] + sb3[n0 + 2], v3 = a3[3] + sb3[n0 + 3];
      if (quad == 3) {  // sigma: trunc_exp -> sig[], gout slot = 0
        float sgm = __expf(fminf(fmaxf(v3, -15.f), 15.f));
        sig[P0 + p] = sgm;
        if constexpr (FIRST) ssig[tt * 64 + p] = sgm;
        v3 = 0.0f;
      }
      *reinterpret_cast<u16x4*>(gout + (size_t)(P0 + p) * 16 + n0) = pack4(v0, v1, v2, v3);
    }
  }

  if constexpr (FIRST) {  // fused sample_pdf (shuffle scans; scratch in buf)
    __syncthreads();  // ssig ready; buf free
    float* psz = reinterpret_cast<float*>(buf);    // [256]
    float* pmid = psz + 256;                       // [256]
    float* pcdf = psz + 512;                       // [256]
    float* psw = psz + 768;                        // [256]
    const int segw = t >> 7;
    const int i = t & 127;
    const int seg = segw * 128;
    const int rg = blockIdx.x * 2 + segw;
    float zi = ray_z(ro, rd, rg, i);
    psz[seg + i] = zi;
    float sgv = ssig[t];
    __syncthreads();
    float aug = (i < 127) ? psz[seg + i + 1] - zi : psz[seg + 127] - psz[seg + 126];
    float alpha = 1.0f - __expf(-aug * sgv);
    float lt = __logf(1.0f - alpha + 1e-15f);
    float s = wave_iscan(lt, lane);        // segmented 128-scan: 2 waves/segment
    if (lane == 63) sred[wid] = s;
    __syncthreads();
    if (wid & 1) s += sred[wid - 1];
    float w = alpha * __expf(s - lt);
    psw[seg + i] = w;
    if (i < 127) pmid[seg + i] = 0.5f * (zi + psz[seg + i + 1]);
    __syncthreads();
    float v2s = (i < 126) ? psw[seg + i + 1] + 1e-5f : 0.f;  // weights[1:-1]+1e-5
    float s2 = wave_iscan(v2s, lane);
    if (lane == 63) sred[8 + wid] = s2;
    __syncthreads();
    if (wid & 1) s2 += sred[8 + wid - 1];
    psw[seg + i] = s2;
    __syncthreads();
    float total = psw[seg + 125];
    if (i <= 126) pcdf[seg + i] = (i == 0) ? 0.f : psw[seg + i - 1] / total;
    __syncthreads();
    const float lo = 0.5f / 128.0f, hi = 1.0f - 0.5f / 128.0f;
    float u = lo + (hi - lo) * ((float)i / 127.0f);
    int loI = 0, hiI = 127;  // searchsorted right over pcdf[seg+0..126]
    while (loI < hiI) {
      int mid = (loI + hiI) >> 1;
      if (pcdf[seg + mid] > u) hiI = mid; else loI = mid + 1;
    }
    int below = loI - 1; if (below < 0) below = 0; if (below > 126) below = 126;
    int above = loI;     if (above > 126) above = 126;
    float c0 = pcdf[seg + below], c1 = pcdf[seg + above];
    float b0v = pmid[seg + below], b1v = pmid[seg + above];
    float dn = c1 - c0; if (dn < 1e-5f) dn = 1.0f;
    float ttt = (u - c0) / dn;
    z_f[rg * NSTEP + i] = b0v + ttt * (b1v - b0v);
  }
}

// --------------------------------------- merge + color MLP + final (per ray)
__global__ __launch_bounds__(256, 2)
void k_mcf(const float* __restrict__ ro, const float* __restrict__ rd,
           const float* __restrict__ z_f,
           const float* __restrict__ sigc, const float* __restrict__ sigf,
           const unsigned short* __restrict__ goutc, const unsigned short* __restrict__ goutf,
           const unsigned short* __restrict__ Wp1, const float* __restrict__ cb1,
           const unsigned short* __restrict__ Wp2, const float* __restrict__ cb2,
           const unsigned short* __restrict__ Wp3, const float* __restrict__ cb3,
           float* __restrict__ out) {
  __shared__ __align__(16) unsigned short buf[64 * 256];
  __shared__ __align__(16) unsigned short xb[64 * 32];
  __shared__ __align__(16) unsigned short sW3[4096];
  __shared__ __align__(16) float sb1[256];
  __shared__ __align__(16) float sb2[256];
  __shared__ __align__(16) float szm[256];
  __shared__ __align__(16) float swgt[256];
  __shared__ __align__(16) float srgb[768];
  __shared__ __align__(16) float sred[48];
  __shared__ unsigned short sord[256];
  const int t = threadIdx.x;
  const int lane = t & 63, wid = t >> 6, quad = lane >> 4, col = lane & 15;
  const int p_ = t >> 2, g_ = t & 3;
  const int r = blockIdx.x;

  sb1[t] = cb1[t];
  sb2[t] = cb2[t];
  { const u16x8* s = (const u16x8*)Wp3; u16x8* d = (u16x8*)sW3;
    d[t] = s[t]; d[t + 256] = s[t + 256]; }

  bf16x8 w1r[4], w2r[8][4];
#pragma unroll
  for (int ntl = 0; ntl < 4; ++ntl)
    w1r[ntl] = *reinterpret_cast<const bf16x8*>(Wp1 + ((wid * 4 + ntl) * 64 + lane) * 8);
#pragma unroll
  for (int kt = 0; kt < 8; ++kt)
#pragma unroll
    for (int ntl = 0; ntl < 4; ++ntl)
      w2r[kt][ntl] = *reinterpret_cast<const bf16x8*>(Wp2 + ((kt * 16 + wid * 4 + ntl) * 64 + lane) * 8);

  // ---- merge phase (stable sort of coarse+fine z); scratch aliased in buf
  float* szc = reinterpret_cast<float*>(buf);
  float* szf = szc + 128;
  if (t < 128) szc[t] = ray_z(ro, rd, r, t);
  else szf[t - 128] = z_f[r * NSTEP + (t - 128)];
  __syncthreads();
  int pos; float myz;
  if (t < 128) {  // coarse i: pos = i + #{zf < zc[i]} (ties: coarse first)
    myz = szc[t];
    int lo = 0, hi = 128;
    while (lo < hi) { int m = (lo + hi) >> 1; if (szf[m] < myz) lo = m + 1; else hi = m; }
    pos = t + lo;
  } else {        // fine j: pos = j + #{zc <= zf[j]}
    int j = t - 128; myz = szf[j];
    int lo = 0, hi = 128;
    while (lo < hi) { int m = (lo + hi) >> 1; if (szc[m] <= myz) lo = m + 1; else hi = m; }
    pos = j + lo;
  }
  szm[pos] = myz; sord[pos] = (unsigned short)t;
  __syncthreads();
  int srci = sord[t];
  float sg = (srci < 128) ? sigc[r * NSTEP + srci] : sigf[r * NSTEP + (srci - 128)];
  float zt = szm[t];
  float aug = (t < 255) ? szm[t + 1] - zt : szm[255] - szm[254];
  float alpha = 1.0f - __expf(-aug * sg);
  float lt = __logf(1.0f - alpha + 1e-15f);
  float incl = block_iscan(lt, sred, lane, wid);  // 1 barrier
  swgt[t] = alpha * __expf(incl - lt);
  __syncthreads();  // swgt/sord ready; buf scratch handoff

  // ---- color phase: 4 tiles; R7 staged gather pipeline -> LDS xb
  float dv0 = rd[r * 3], dv1 = rd[r * 3 + 1], dv2 = rd[r * 3 + 2];
  u16x8 dirpk = {f2bf(dv0), f2bf(dv1), f2bf(dv2), 0, 0, 0, 0, 0};
  u16x8 gx = {0, 0, 0, 0, 0, 0, 0, 0};
  float wgtv = 0.0f;
  { // prologue gather (tile 0)
    if (g_ < 2) {
      int s0 = sord[p_];
      const unsigned short* gs = ((s0 < 128) ? goutc : goutf)
          + ((size_t)(r * NSTEP + (s0 & 127)) * 16) + g_ * 8;
      gx = *reinterpret_cast<const u16x8*>(gs);
    } else if (g_ == 2) {
      gx = dirpk;
    } else {
      wgtv = swgt[p_];
    }
  }
#pragma unroll 1
  for (int tt = 0; tt < 4; ++tt) {
    const int haveNext = (tt < 3);
    int go = __syncthreads_or((g_ == 3) && (wgtv > 1e-4f));
    int ordn = 0; float wgtn = 0.0f;
    u16x8 gxn = {0, 0, 0, 0, 0, 0, 0, 0};
    if (go) {
      *reinterpret_cast<u16x8*>(&xb[p_ * 32 + ((g_ ^ (p_ & 3)) * 8)]) = gx;
      __syncthreads();  // xb ready; prev tile's L3 buf-reads retired
      mlp_l1(xb, buf, w1r, sb1, wid, quad, col);
      __syncthreads();  // h1 complete
    }
    if (haveNext) {  // stage 1: LDS order/wgt + uniform dir
      int Pn = (tt + 1) * 64 + p_;
      if (g_ < 2) ordn = sord[Pn];
      else if (g_ == 2) gxn = dirpk;
      else wgtn = swgt[Pn];
    }
    f32x4 acc[8];
    if (go) {
      l2_half_compute(buf, w2r, acc, 0, quad, col);
      __syncthreads();  // fence: half0 reads done before overwrite
      l2_half_write(buf, acc, sb2, 0, wid, quad, col);
    }
    if (haveNext && g_ < 2) {  // stage 2: global gout gather
      const unsigned short* gs = ((ordn < 128) ? goutc : goutf)
          + ((size_t)(r * NSTEP + (ordn & 127)) * 16) + g_ * 8;
      gxn = *reinterpret_cast<const u16x8*>(gs);
    }
    if (go) {
      l2_half_compute(buf, w2r, acc, 1, quad, col);
      __syncthreads();  // fence: half1 reads done
      l2_half_write(buf, acc, sb2, 1, wid, quad, col);
      __syncthreads();  // h2 complete
      { // L3: 256 -> 3, sigmoid -> srgb (LDS sW3, R7-proven)
        const int p = wid * 16 + col;
        f32x4 a3 = {0.f, 0.f, 0.f, 0.f};
#pragma unroll
        for (int kt = 0; kt < 8; ++kt) {
          bf16x8 w = *reinterpret_cast<const bf16x8*>(&sW3[(kt * 64 + lane) * 8]);
          bf16x8 xx = *reinterpret_cast<const bf16x8*>(&buf[p * 256 + (((kt * 4 + quad) ^ (p & 31)) * 8)]);
          a3 = __builtin_amdgcn_mfma_f32_16x16x32_bf16(w, xx, a3, 0, 0, 0);
        }
        if (quad == 0) {
          int pi = tt * 64 + p;
          srgb[pi * 3 + 0] = 1.0f / (1.0f + __expf(-(a3[0] + cb3[0])));
          srgb[pi * 3 + 1] = 1.0f / (1.0f + __expf(-(a3[1] + cb3[1])));
          srgb[pi * 3 + 2] = 1.0f / (1.0f + __expf(-(a3[2] + cb3[2])));
        }
      }
    }
    gx = gxn; wgtv = wgtn;
  }

  // ---- final: image/depth + distortion loss via sorted prefix sums
  __syncthreads();  // srgb ready
  float ztf = szm[t], wtf = swgt[t];
  float znext = (t < 255) ? szm[t + 1] : (1.0f / 128.0f);  // sample_dist
  float mt = 0.5f * ztf + 0.5f * znext;  // sorted for t<=254; t=255 is outlier
  float cr = 0.f, cg = 0.f, cbl = 0.f;
  if (wtf > 1e-4f) { cr = srgb[t * 3]; cg = srgb[t * 3 + 1]; cbl = srgb[t * 3 + 2]; }
  if (t == 255) { sred[36] = mt; sred[37] = wtf; }
  float wm = (t < 255) ? wtf : 0.f;
  float Pw = block_iscan(wm, sred, lane, wid);
  float Ps = block_iscan(wm * mt, sred + 4, lane, wid);
  float W254 = sred[0] + sred[1] + sred[2] + sred[3];
  float S254 = sred[4] + sred[5] + sred[6] + sred[7];
  float m255 = sred[36], w255 = sred[37];
  float contrib = 0.f;
  if (t < 255)
    contrib = wtf * (mt * (2.f * Pw - W254) - (2.f * Ps - S254))
            + 2.f * wtf * fabsf(mt - m255) * w255;
  float vals[6] = {wtf, wtf * ztf, wtf * cr, wtf * cg, wtf * cbl, contrib};
#pragma unroll
  for (int k = 0; k < 6; ++k) {
    float v = vals[k];
#pragma unroll
    for (int m = 1; m < 64; m <<= 1) v += __shfl_xor(v, m, 64);
    if (lane == 0) sred[8 + k * 4 + wid] = v;
  }
  __syncthreads();
  if (t == 0) {
    float a6[6];
#pragma unroll
    for (int k = 0; k < 6; ++k)
      a6[k] = sred[8 + k * 4] + sred[8 + k * 4 + 1] + sred[8 + k * 4 + 2] + sred[8 + k * 4 + 3];
    const float bgc = 206.0f / 255.0f;
    float wsum = a6[0], depth = a6[1];
    float loss = a6[5] / (depth + 1e-6f);
    if (loss < 1e-3f) loss = 0.0f;
    out[r * 5 + 0] = a6[2] + (1.0f - wsum) * bgc;
    out[r * 5 + 1] = a6[3] + (1.0f - wsum) * bgc;
    out[r * 5 + 2] = a6[4] + (1.0f - wsum) * bgc;
    out[r * 5 + 3] = depth;
    out[r * 5 + 4] = loss;
  }
}

// ---------------------------------------------------------------- launch
extern "C" void kernel_launch(void* const* d_in, const int* in_sizes, int n_in,
                              void* d_out, int out_size, void* d_ws, size_t ws_size,
                              hipStream_t stream) {
  const float* rays_o = (const float*)d_in[0];
  const float* rays_d = (const float*)d_in[1];
  const float* dW1 = (const float*)d_in[2];
  const float* db1 = (const float*)d_in[3];
  const float* dW2 = (const float*)d_in[4];
  const float* db2 = (const float*)d_in[5];
  const float* dW3 = (const float*)d_in[6];
  const float* db3 = (const float*)d_in[7];
  const float* cW1 = (const float*)d_in[8];
  const float* cb1 = (const float*)d_in[9];
  const float* cW2 = (const float*)d_in[10];
  const float* cb2 = (const float*)d_in[11];
  const float* cW3 = (const float*)d_in[12];
  const float* cb3 = (const float*)d_in[13];
  // num_steps / upsample_steps fixed at 128/128 (compile-time).

  char* ws = (char*)d_ws;
  size_t off = 0;
  auto alloc = [&](size_t bytes) -> void* {
    void* p = ws + off;
    off += (bytes + 255) & ~(size_t)255;
    return p;
  };
  unsigned short* Wp = (unsigned short*)alloc((size_t)PACK_TOTAL * 2);
  unsigned short* goutc = (unsigned short*)alloc((size_t)NRAYS * NSTEP * 16 * 2);
  unsigned short* goutf = (unsigned short*)alloc((size_t)NRAYS * NSTEP * 16 * 2);
  float* sigc = (float*)alloc((size_t)NRAYS * NSTEP * 4);
  float* sigf = (float*)alloc((size_t)NRAYS * NSTEP * 4);
  float* z_f  = (float*)alloc((size_t)NRAYS * NSTEP * 4);
  (void)ws_size; (void)in_sizes; (void)n_in; (void)out_size;

  k_pack_all<<<PACK_TOTAL / 256, 256, 0, stream>>>(dW1, dW2, dW3, cW1, cW2, cW3, Wp);

  k_density<true><<<(NRAYS * NSTEP) / 256, 256, 0, stream>>>(
      rays_o, rays_d, nullptr,
      Wp + OFF_D1, db1, Wp + OFF_D2, db2, Wp + OFF_D3, db3, goutc, sigc, z_f);
  k_density<false><<<(NRAYS * NSTEP) / 256, 256, 0, stream>>>(
      rays_o, rays_d, z_f,
      Wp + OFF_D1, db1, Wp + OFF_D2, db2, Wp + OFF_D3, db3, goutf, sigf, nullptr);
  k_mcf<<<NRAYS, 256, 0, stream>>>(
      rays_o, rays_d, z_f, sigc, sigf, goutc, goutf,
      Wp + OFF_C1, cb1, Wp + OFF_C2, cb2, Wp + OFF_C3, cb3, (float*)d_out);
}